// Round 7
// baseline (514.971 us; speedup 1.0000x reference)
//
#include <hip/hip_runtime.h>
#include <stdint.h>

typedef float v4f __attribute__((ext_vector_type(4)));
typedef short v8s __attribute__((ext_vector_type(8)));

#define SZ_BHTD 8388608   // B*H*T*DH
#define SZ_HTD  131072    // T*DH

#define GL2LDS(g, l) __builtin_amdgcn_global_load_lds( \
    (const __attribute__((address_space(1))) void*)(g), \
    (__attribute__((address_space(3))) void*)(l), 16, 0, 0)

#define MFMA(a, b, c) __builtin_amdgcn_mfma_f32_16x16x32_bf16(a, b, c, 0, 0, 0)

__device__ __forceinline__ uint16_t f2bf(float f){
  uint32_t u = __float_as_uint(f);
  u += 0x7fffu + ((u >> 16) & 1u);
  return (uint16_t)(u >> 16);
}
__device__ __forceinline__ float bf2f(uint16_t v){
  return __uint_as_float(((uint32_t)v) << 16);
}

// device-scope grid barrier: 512 blocks, one-shot counter (zeroed per launch)
__device__ __forceinline__ void gbar(int* ctr){
  __syncthreads();
  if (threadIdx.x == 0){
    __threadfence();
    atomicAdd(ctr, 1);
    while (__atomic_load_n((const volatile int*)ctr, __ATOMIC_ACQUIRE) < 512)
      __builtin_amdgcn_s_sleep(2);
    __threadfence();
  }
  __syncthreads();
}

// Fused conversions: [0,8192): x fp32->bf16; [8192,8960): W transpose->bf16; [8960,8976): pkv^T bf16
__global__ __launch_bounds__(256) void k_conv(const float* __restrict__ x,
                                              const float* __restrict__ Wq, const float* __restrict__ Wk,
                                              const float* __restrict__ Wv, const float* __restrict__ pkv,
                                              uint16_t* __restrict__ xb, uint16_t* __restrict__ wt,
                                              uint16_t* __restrict__ pkvT){
  if (blockIdx.x < 8192){
    int i = blockIdx.x*256 + threadIdx.x;
    const float4 v = ((const float4*)x)[i];
    ushort4 o; o.x = f2bf(v.x); o.y = f2bf(v.y); o.z = f2bf(v.z); o.w = f2bf(v.w);
    ((ushort4*)xb)[i] = o;
    return;
  }
  __shared__ float t[64][65];
  if (blockIdx.x >= 8960){
    const int h = blockIdx.x - 8960;
    for (int idx = threadIdx.x; idx < 4096; idx += 256)
      t[idx >> 6][idx & 63] = pkv[h*4096 + idx];          // t[d][e]
    __syncthreads();
    for (int idx = threadIdx.x; idx < 4096; idx += 256){
      int e = idx >> 6, d = idx & 63;
      pkvT[h*4096 + idx] = f2bf(t[d][e]);                 // pkvT[h][e][d]
    }
    return;
  }
  const int blk2 = blockIdx.x - 8192;          // [0,768)
  const int z = blk2 >> 8, y = (blk2 >> 4) & 15, xx = blk2 & 15;
  const float* W = z==0 ? Wq : (z==1 ? Wk : Wv);
  int n0 = xx*64, k0 = y*64;
  for (int idx = threadIdx.x; idx < 4096; idx += 256){
    int r = idx >> 6, c = idx & 63;
    t[r][c] = W[(k0+r)*1024 + n0 + c];
  }
  __syncthreads();
  for (int idx = threadIdx.x; idx < 4096; idx += 256){
    int r = idx >> 6, c = idx & 63;   // r: local n, c: local k
    wt[(size_t)(z*1024 + n0 + r)*1024 + k0 + c] = f2bf(t[c][r]);
  }
}

// QKV GEMM, 128x128 tile, BK=64, global_load_lds + XOR swizzle (conflict-free).
// Outputs: Q,K row-major (scattered b16); K^T, V^T per-chunk via LDS bounce -> coalesced uint4.
__global__ __launch_bounds__(256) void k_gemm(const uint16_t* __restrict__ Xb, const uint16_t* __restrict__ Wt,
                                              uint16_t* __restrict__ qkv, uint16_t* __restrict__ KTg){
  __shared__ uint16_t smem[16384];   // As+Bs during K-loop; T2 in epilogue
  uint16_t* As = smem;
  uint16_t* Bs = smem + 8192;
  const int tid = threadIdx.x;
  const int lane = tid & 63, w = tid >> 6;
  const int quad = lane >> 4, l16 = lane & 15;
  const int wm = (w >> 1)*64, wn = (w & 1)*64;
  const int bm = blockIdx.x, bn = blockIdx.y;
  v4f acc[4][4] = {};
  const uint16_t* Ag = Xb + (size_t)(bm*128)*1024;
  const uint16_t* Bg = Wt + (size_t)(bn*128)*1024;
  const int rA = lane >> 3;
  const int ce = (((lane & 7) ^ rA) * 8);
  const int xr = l16 & 7;
  for (int k0 = 0; k0 < 1024; k0 += 64){
    #pragma unroll
    for (int j = 0; j < 4; ++j){
      const int cA = w*4 + j;
      const int r = cA*8 + rA;
      GL2LDS(Ag + (size_t)r*1024 + k0 + ce, As + cA*512);
      GL2LDS(Bg + (size_t)r*1024 + k0 + ce, Bs + cA*512);
    }
    __syncthreads();
    #pragma unroll
    for (int kk = 0; kk < 64; kk += 32){
      const int ch = ((quad + (kk >> 3)) ^ xr) * 8;
      v8s a[4], b[4];
      #pragma unroll
      for (int u = 0; u < 4; ++u) a[u] = *(v8s*)&As[(wm + u*16 + l16)*64 + ch];
      #pragma unroll
      for (int u = 0; u < 4; ++u) b[u] = *(v8s*)&Bs[(wn + u*16 + l16)*64 + ch];
      #pragma unroll
      for (int mi = 0; mi < 4; ++mi)
        #pragma unroll
        for (int ni = 0; ni < 4; ++ni)
          acc[mi][ni] = MFMA(a[mi], b[ni], acc[mi][ni]);
    }
    __syncthreads();
  }
  const int which = bn >> 3;   // 0:Q 1:K 2:V
  if (which < 2){
    const size_t base_rm = (size_t)which*SZ_BHTD;
    #pragma unroll
    for (int mi = 0; mi < 4; ++mi){
      const int m0 = bm*128 + wm + mi*16 + quad*4;
      const int b = m0 >> 11, t0 = m0 & 2047;
      #pragma unroll
      for (int ni = 0; ni < 4; ++ni){
        const int n = bn*128 + wn + ni*16 + l16;
        const int hh = (n & 1023) >> 6, dd = n & 63;
        #pragma unroll
        for (int r = 0; r < 4; ++r)
          qkv[base_rm + (size_t)((b*16 + hh)*2048 + t0 + r)*64 + dd] = f2bf(acc[mi][ni][r]);
      }
    }
  }
  if (which >= 1){
    #pragma unroll
    for (int mi = 0; mi < 4; ++mi){
      const int m_base = wm + mi*16 + quad*4;
      const int chunk = m_base >> 3, mo = m_base & 7;
      #pragma unroll
      for (int ni = 0; ni < 4; ++ni){
        const int n_loc = wn + ni*16 + l16;
        uint2 pk;
        pk.x = (uint32_t)f2bf(acc[mi][ni][0]) | ((uint32_t)f2bf(acc[mi][ni][1]) << 16);
        pk.y = (uint32_t)f2bf(acc[mi][ni][2]) | ((uint32_t)f2bf(acc[mi][ni][3]) << 16);
        *(uint2*)&smem[n_loc*128 + ((chunk ^ (n_loc & 15)) << 3) + mo] = pk;
      }
    }
    __syncthreads();
    uint16_t* dstbase = (which == 1) ? KTg : (qkv + 2*(size_t)SZ_BHTD);
    #pragma unroll
    for (int rep = 0; rep < 8; ++rep){
      const int n_loc = (tid >> 4) + rep*16;
      const int u = tid & 15;
      uint4 vv = *(uint4*)&smem[n_loc*128 + ((u ^ (n_loc & 15)) << 3)];
      const int n = bn*128 + n_loc;
      const int hh = (n & 1023) >> 6, dd = n & 63;
      const int m0 = bm*128 + u*8;
      const int b = m0 >> 11, t0 = m0 & 2047;
      const int cc = t0 >> 6, s0 = t0 & 63;
      *(uint4*)&dstbase[((size_t)(b*16 + hh)*32 + cc)*4096 + dd*64 + s0] = vv;
    }
  }
}

// Persistent fused middle: phase1 per-chunk summaries (U,CK,head) -> barrier ->
// phase2 fwd state scan + bwd tail scan -> barrier -> phase3 main retention (-> ret, pb)
// -> barrier -> phase4 GroupNorm + current_kv. 512 blocks, 4 chunks/block.
__global__ __launch_bounds__(256, 4) void k_mega(
    const uint16_t* __restrict__ qkv, const uint16_t* __restrict__ KTg,
    const float* __restrict__ pkv, const uint16_t* __restrict__ pkvT,
    const float* __restrict__ gnw, const float* __restrict__ gnb,
    uint16_t* __restrict__ UT, uint16_t* __restrict__ ckp, uint16_t* __restrict__ S,
    float* __restrict__ headv, float* __restrict__ tailv,
    uint16_t* __restrict__ ret, float2* __restrict__ pb,
    float* __restrict__ out, float* __restrict__ out2, int* __restrict__ bar){
  __shared__ uint16_t smA[64*72];   // phase3: Pl; phase1: float alias qp/qbar/hp
  __shared__ uint16_t smB[64*72];   // phase3: Tp
  __shared__ float tab[65];
  __shared__ float ps[8];
  __shared__ float mv[2];
  const int tid = threadIdx.x, blk = blockIdx.x;
  const int bh = blk >> 3, part = blk & 7, h = bh & 15;
  const int lane = tid & 63, w = tid >> 6;
  const int quad = lane >> 4, l16 = lane & 15;
  const float g = 1.0f - exp2f(-(float)(5 + h));
  if (tid <= 64) tab[tid] = powf(g, (float)tid);
  __syncthreads();
  float* fA = (float*)smA;          // qp[0..255] | qbar[256..319] | hp[320..575]
  const int row = w*16 + l16;

  // ---------- phase 1: per-chunk U, CK, head ----------
  for (int j = 0; j < 4; ++j){
    const int c = part*4 + j;
    const int bc = bh*32 + c;
    const uint16_t* Qg = qkv + (size_t)bh*SZ_HTD + c*4096;
    const uint16_t* KT = KTg + (size_t)bc*4096;
    const uint16_t* VT = qkv + 2*(size_t)SZ_BHTD + (size_t)bc*4096;
    const float* Pg = pkv + h*4096;
    v8s aK0 = *(const v8s*)&KT[row*64 + quad*8];
    v8s aK1 = *(const v8s*)&KT[row*64 + 32 + quad*8];
    v8s vt0 = *(const v8s*)&VT[row*64 + quad*8];
    v8s vt1 = *(const v8s*)&VT[row*64 + 32 + quad*8];
    v8s aW0, aW1;
    #pragma unroll
    for (int u = 0; u < 8; ++u){
      aW0[u] = (short)f2bf(tab[63 - (quad*8 + u)]*bf2f((uint16_t)vt0[u]));
      aW1[u] = (short)f2bf(tab[31 - (quad*8 + u)]*bf2f((uint16_t)vt1[u]));
    }
    v4f accC[4] = {}, accU[4] = {};
    #pragma unroll
    for (int ni = 0; ni < 4; ++ni){
      const int br = (ni*16 + l16)*64 + quad*8;
      v8s bV0 = *(const v8s*)&VT[br], bV1 = *(const v8s*)&VT[br + 32];
      v8s bK0 = *(const v8s*)&KT[br], bK1 = *(const v8s*)&KT[br + 32];
      accC[ni] = MFMA(aK0, bV0, accC[ni]);
      accC[ni] = MFMA(aK1, bV1, accC[ni]);
      accU[ni] = MFMA(aW0, bK0, accU[ni]);
      accU[ni] = MFMA(aW1, bK1, accU[ni]);
    }
    const size_t ob = (size_t)bc*4096;
    #pragma unroll
    for (int ni = 0; ni < 4; ++ni){
      int e = ni*16 + l16;
      #pragma unroll
      for (int r = 0; r < 4; ++r){
        int d = w*16 + quad*4 + r;
        ckp[ob + d*64 + e] = f2bf(accC[ni][r]);
        UT[ob + d*64 + e]  = f2bf(accU[ni][r]);
      }
    }
    {
      int d = tid & 63, jg = tid >> 6;
      float a = 0.f;
      #pragma unroll
      for (int jj = 0; jj < 16; ++jj)
        a = fmaf(tab[jg*16 + jj], bf2f(Qg[(jg*16 + jj)*64 + d]), a);
      fA[jg*64 + d] = a;
    }
    __syncthreads();
    if (tid < 64) fA[256 + tid] = fA[tid] + fA[64 + tid] + fA[128 + tid] + fA[192 + tid];
    __syncthreads();
    {
      int e = tid & 63, dg = tid >> 6;
      float a = 0.f;
      #pragma unroll
      for (int dd = 0; dd < 16; ++dd)
        a = fmaf(fA[256 + dg*16 + dd], Pg[(dg*16 + dd)*64 + e], a);
      fA[320 + dg*64 + e] = a;
    }
    __syncthreads();
    if (tid < 64) headv[(size_t)bc*64 + tid] = fA[320 + tid] + fA[384 + tid] + fA[448 + tid] + fA[512 + tid];
    __syncthreads();
  }
  gbar(&bar[0]);

  // ---------- phase 2: forward state scan + backward tail scan ----------
  {
    const int tg = blk*256 + tid;
    if (tg < 65536){
      const int bh_s = tg >> 10, off4 = (tg & 1023)*4;
      const float gs = 1.0f - exp2f(-(float)(5 + (bh_s & 15)));
      const float g64 = powf(gs, 64.0f);
      float st0=0.f, st1=0.f, st2=0.f, st3=0.f;
      for (int c = 0; c < 32; ++c){
        const size_t base = ((size_t)bh_s*32 + c)*4096 + off4;
        ushort4 u = *(const ushort4*)&UT[base];
        ushort4 o; o.x=f2bf(st0); o.y=f2bf(st1); o.z=f2bf(st2); o.w=f2bf(st3);
        *(ushort4*)&S[base] = o;
        st0 = fmaf(g64, st0, bf2f(u.x)); st1 = fmaf(g64, st1, bf2f(u.y));
        st2 = fmaf(g64, st2, bf2f(u.z)); st3 = fmaf(g64, st3, bf2f(u.w));
      }
    } else if (tg < 69632){
      const int lin = tg - 65536;
      const int bh_s = lin >> 6, e = lin & 63;
      const float gs = 1.0f - exp2f(-(float)(5 + (bh_s & 15)));
      const float g64 = powf(gs, 64.0f);
      float R = 0.0f;
      for (int c = 31; c >= 0; --c){
        const size_t o = ((size_t)bh_s*32 + c)*64 + e;
        tailv[o] = R;
        R = fmaf(g64, R, headv[o]);
      }
    }
  }
  gbar(&bar[1]);

  // ---------- phase 3: main retention ----------
  float s1 = 0.f, s2 = 0.f;
  for (int j = 0; j < 4; ++j){
    const int c = part*4 + j;
    const int bc = bh*32 + c;
    const uint16_t* Qg = qkv + (size_t)bh*SZ_HTD + c*4096;
    const uint16_t* Kg = Qg + SZ_BHTD;
    const uint16_t* VT = qkv + 2*(size_t)SZ_BHTD + (size_t)bc*4096;
    const uint16_t* Sgp = S + (size_t)bc*4096;
    const uint16_t* PT = pkvT + h*4096;
    v8s aQ0 = *(const v8s*)&Qg[row*64 + quad*8];
    v8s aQ1 = *(const v8s*)&Qg[row*64 + 32 + quad*8];
    v4f accP[4] = {}, accPP[4] = {}, accIT[4] = {};
    #pragma unroll
    for (int ni = 0; ni < 4; ++ni){
      const int br = (ni*16 + l16)*64 + quad*8;
      v8s b0 = *(const v8s*)&Kg[br], b1 = *(const v8s*)&Kg[br + 32];
      accP[ni] = MFMA(aQ0, b0, accP[ni]);
      accP[ni] = MFMA(aQ1, b1, accP[ni]);
      v8s c0 = *(const v8s*)&PT[br], c1 = *(const v8s*)&PT[br + 32];
      accPP[ni] = MFMA(aQ0, c0, accPP[ni]);
      accPP[ni] = MFMA(aQ1, c1, accPP[ni]);
      v8s d0 = *(const v8s*)&Sgp[br], d1 = *(const v8s*)&Sgp[br + 32];
      accIT[ni] = MFMA(aQ0, d0, accIT[ni]);
      accIT[ni] = MFMA(aQ1, d1, accIT[ni]);
    }
    __syncthreads();   // prior-iteration smA/smB reads complete
    #pragma unroll
    for (int ni = 0; ni < 4; ++ni){
      #pragma unroll
      for (int r = 0; r < 4; ++r){
        int i = w*16 + quad*4 + r;
        int jj = ni*16 + l16;
        smA[i*72 + jj] = f2bf((i >= jj) ? accP[ni][r]*tab[i - jj] : 0.0f);   // P'
        smB[jj*72 + i] = f2bf(accPP[ni][r]);                                 // ppT
      }
    }
    __syncthreads();
    v8s aP0 = *(v8s*)&smA[row*72 + quad*8], aP1 = *(v8s*)&smA[row*72 + 32 + quad*8];
    v8s aM0, aM1;
    {
      int i = row;
      #pragma unroll
      for (int u = 0; u < 8; ++u){
        int j0 = quad*8 + u, j1 = 32 + quad*8 + u;
        aM0[u] = (short)f2bf((j0 >= i) ? tab[j0 - i] : 0.0f);
        aM1[u] = (short)f2bf((j1 >= i) ? tab[j1 - i] : 0.0f);
      }
    }
    v4f accI[4] = {}, accX[4] = {};
    #pragma unroll
    for (int ni = 0; ni < 4; ++ni){
      const int bg = (ni*16 + l16)*64 + quad*8;
      v8s b0 = *(const v8s*)&VT[bg], b1 = *(const v8s*)&VT[bg + 32];
      accI[ni] = MFMA(aP0, b0, accI[ni]);
      accI[ni] = MFMA(aP1, b1, accI[ni]);
      const int bl = (ni*16 + l16)*72 + quad*8;
      v8s e0 = *(v8s*)&smB[bl], e1 = *(v8s*)&smB[bl + 32];
      accX[ni] = MFMA(aM0, e0, accX[ni]);
      accX[ni] = MFMA(aM1, e1, accX[ni]);
    }
    const size_t rbase = (size_t)bh*2048 + (size_t)c*64;
    #pragma unroll
    for (int ni = 0; ni < 4; ++ni){
      int d = ni*16 + l16;
      float tl = tailv[(size_t)bc*64 + d];
      #pragma unroll
      for (int r = 0; r < 4; ++r){
        int i = w*16 + quad*4 + r;
        float v = accI[ni][r] + tab[i + 1]*accIT[ni][r] + accX[ni][r] + tab[64 - i]*tl;
        ret[(rbase + i)*64 + d] = f2bf(v);
        s1 += v; s2 += v*v;
      }
    }
  }
  #pragma unroll
  for (int off = 32; off > 0; off >>= 1){
    s1 += __shfl_down(s1, off);
    s2 += __shfl_down(s2, off);
  }
  __syncthreads();   // smA/smB reads done before ps reuse safety
  if (lane == 0){ ps[w*2] = s1; ps[w*2+1] = s2; }
  __syncthreads();
  if (tid == 0){
    float2 o; o.x = ps[0] + ps[2] + ps[4] + ps[6];
    o.y = ps[1] + ps[3] + ps[5] + ps[7];
    pb[blk] = o;
  }
  gbar(&bar[2]);

  // ---------- phase 4: GroupNorm + current_kv ----------
  {
    const int b4 = blk >> 7;   // batch
    float t1 = 0.f, t2 = 0.f;
    if (tid < 128){
      float2 p = pb[b4*128 + tid];
      t1 = p.x; t2 = p.y;
    }
    #pragma unroll
    for (int off = 32; off > 0; off >>= 1){
      t1 += __shfl_down(t1, off);
      t2 += __shfl_down(t2, off);
    }
    if (lane == 0){ ps[w*2] = t1; ps[w*2+1] = t2; }
    __syncthreads();
    if (tid == 0){
      const float inv = 1.0f/2097152.0f;
      const float mu = (ps[0] + ps[2] + ps[4] + ps[6])*inv;
      const float var = (ps[1] + ps[3] + ps[5] + ps[7])*inv - mu*mu;
      mv[0] = mu; mv[1] = rsqrtf(var + 1e-5f);
    }
    __syncthreads();
    const float mu = mv[0], rs = mv[1];
    #pragma unroll 4
    for (int it = 0; it < 16; ++it){
      const int o = blk*16384 + (it*256 + tid)*4;
      const int t = (o >> 10) & 2047, cch = o & 1023;
      const int hh = cch >> 6, d = cch & 63;
      const float ww = gnw[hh]*rs, bb = gnb[hh];
      const ushort4 v = *(const ushort4*)&ret[((size_t)(b4*16 + hh)*2048 + t)*64 + d];
      float4 r;
      r.x = (bf2f(v.x) - mu)*ww + bb; r.y = (bf2f(v.y) - mu)*ww + bb;
      r.z = (bf2f(v.z) - mu)*ww + bb; r.w = (bf2f(v.w) - mu)*ww + bb;
      *(float4*)&out[o] = r;
    }
    if (tid < 128){
      const int i = blk*128 + tid;          // [0,65536)
      const int hh = i >> 12;
      const float gl = 1.0f - exp2f(-(float)(5 + hh));
      float acc = 0.0f;
      #pragma unroll
      for (int b = 0; b < 4; ++b){
        const uint16_t* base = ckp + ((size_t)(b*16 + hh)*32)*4096 + (i & 4095);
        for (int c = 0; c < 32; ++c) acc += bf2f(base[(size_t)c*4096]);
      }
      out2[i] = fmaf(gl, pkv[i], 0.25f*acc);
    }
  }
}

extern "C" void kernel_launch(void* const* d_in, const int* in_sizes, int n_in,
                              void* d_out, int out_size, void* d_ws, size_t ws_size,
                              hipStream_t stream){
  const float* x   = (const float*)d_in[0];
  const float* pkv = (const float*)d_in[1];
  const float* Wq  = (const float*)d_in[2];
  const float* Wk  = (const float*)d_in[3];
  const float* Wv  = (const float*)d_in[4];
  const float* gnw = (const float*)d_in[5];
  const float* gnb = (const float*)d_in[6];
  float* out  = (float*)d_out;
  float* out2 = out + 8388608;

  char* ws = (char*)d_ws;
  size_t off = 0;
  int*      bar   = (int*)(ws + off);      off += 256;
  float2*   pb    = (float2*)(ws + off);   off += (size_t)512*8;
  uint16_t* Xb    = (uint16_t*)(ws + off); off += (size_t)8388608*2;
  uint16_t* Wt    = (uint16_t*)(ws + off); off += (size_t)3145728*2;
  uint16_t* QKV   = (uint16_t*)(ws + off); off += (size_t)3*8388608*2;   // Q, K, V^T
  uint16_t* KTg   = (uint16_t*)(ws + off); off += (size_t)8388608*2;
  uint16_t* ret   = (uint16_t*)(ws + off); off += (size_t)8388608*2;
  uint16_t* UT    = (uint16_t*)(ws + off); off += (size_t)8388608*2;
  uint16_t* S     = (uint16_t*)(ws + off); off += (size_t)8388608*2;
  uint16_t* CKp   = (uint16_t*)(ws + off); off += (size_t)8388608*2;
  uint16_t* pkvT  = (uint16_t*)(ws + off); off += (size_t)65536*2;
  float*    headv = (float*)(ws + off);    off += (size_t)131072*4;
  float*    tailv = (float*)(ws + off);    off += (size_t)131072*4;

  hipMemsetAsync(bar, 0, 256, stream);
  k_conv<<<8976, 256, 0, stream>>>(x, Wq, Wk, Wv, pkv, Xb, Wt, pkvT);
  k_gemm<<<dim3(64, 24), 256, 0, stream>>>(Xb, Wt, QKV, KTg);
  k_mega<<<512, 256, 0, stream>>>(QKV, KTg, pkv, pkvT, gnw, gnb,
                                  UT, CKp, S, headv, tailv, ret, pb, out, out2, bar);
}